// Round 2
// baseline (528.376 us; speedup 1.0000x reference)
//
#include <hip/hip_runtime.h>

// FlowNet correlation, kernel_size=1, max_disp=4.
// out[b, (dy+4)*9+(dx+4), y, x] = (1/C) * sum_c in1[b,c,y,x]*in2[b,c,y+dy,x+dx]
//
// Block = 8x64 output tile, 576 thr = 9 waves, wave w owns dy=w (uniform).
// Thread = (dy, yi, xt): 8 consecutive x, acc[9 dx][8 x] in regs.
// C staged in CK=8 chunks through LDS with T14 async reg-prefetch:
//   barrier; ds_write(prefetched regs); barrier; issue next global loads;
//   compute -- so HBM latency hides under the ~10k-cycle FMA phase.
// Lane map yi=lane&7 (rows vary fastest within 8-lane phases) + row strides
// 68/76 floats (=4/12 mod 32 banks) -> conflict-free b128 LDS reads.

#define BB 8
#define CC 96
#define HH 160
#define WW 320
#define TY 8
#define TX 64
#define CK 8
#define NCH (CC / CK)   // 12
#define S1W 68
#define S2W 76
#define NT 576
#define HWSZ (HH * WW)  // 51200

__global__ __launch_bounds__(NT, 1)
void corr_kernel(const float* __restrict__ in1,
                 const float* __restrict__ in2,
                 float* __restrict__ out) {
    const int x0 = blockIdx.x * TX;
    const int y0 = blockIdx.y * TY;
    const int b  = blockIdx.z;

    const int tid  = threadIdx.x;
    const int dy   = tid >> 6;       // 0..8, uniform per wave
    const int lane = tid & 63;
    const int yi   = lane & 7;       // rows vary fastest -> bank spread
    const int xt   = lane >> 3;      // 0..7 -> 8-pixel x sub-block

    __shared__ float s1[CK][TY][S1W];
    __shared__ float s2[CK][TY + 8][S2W];

    // ---- precompute staging addresses (loop-invariant) ----
    // in1 tile: CK*8*64 floats = 1024 float4; thread loads i=tid, +576 if tid<448
    const float* g1a;
    float4* l1a;
    {
        const int i = tid, k = i >> 7, rem = i & 127, yy = rem >> 4, xg = rem & 15;
        g1a = in1 + ((b * CC + k) * HH + y0 + yy) * WW + x0 + 4 * xg;
        l1a = (float4*)&s1[k][yy][4 * xg];
    }
    const bool has1b = (tid < 448);            // waves 0-6: uniform per wave
    const float* g1b = in1;
    float4* l1b = (float4*)&s1[0][0][0];
    if (has1b) {
        const int i = tid + NT, k = i >> 7, rem = i & 127, yy = rem >> 4, xg = rem & 15;
        g1b = in1 + ((b * CC + k) * HH + y0 + yy) * WW + x0 + 4 * xg;
        l1b = (float4*)&s1[k][yy][4 * xg];
    }
    // in2 halo tile: CK*16*18 = 2304 float4, 4 per thread, zero-fill OOB
    const float* g2[4];
    float4* l2[4];
    bool ok2[4];
#pragma unroll
    for (int j = 0; j < 4; ++j) {
        const int i = tid + j * NT;
        const int k = i / 288, rem = i % 288, r = rem / 18, xg = rem % 18;
        const int yy = y0 + r - 4, xs = x0 - 4 + 4 * xg;
        ok2[j] = ((unsigned)yy < (unsigned)HH) && ((unsigned)xs <= (unsigned)(WW - 4));
        g2[j] = in2 + ((b * CC + k) * HH + (ok2[j] ? yy : 0)) * WW + (ok2[j] ? xs : 0);
        l2[j] = (float4*)&s2[k][r][4 * xg];
    }

    const float4 z4 = make_float4(0.f, 0.f, 0.f, 0.f);
    float4 p1a, p1b, p2[4];

    // ---- prologue: prefetch chunk 0 ----
    p1a = *(const float4*)g1a;
    p1b = has1b ? *(const float4*)g1b : z4;
#pragma unroll
    for (int j = 0; j < 4; ++j) p2[j] = ok2[j] ? *(const float4*)g2[j] : z4;

    float acc[9][8];
#pragma unroll
    for (int i = 0; i < 9; ++i)
#pragma unroll
        for (int j = 0; j < 8; ++j) acc[i][j] = 0.0f;

    for (int ch = 0; ch < NCH; ++ch) {
        __syncthreads();                 // readers of previous chunk done
        *l1a = p1a;
        if (has1b) *l1b = p1b;
#pragma unroll
        for (int j = 0; j < 4; ++j) *l2[j] = p2[j];
        __syncthreads();                 // tile visible

        if (ch + 1 < NCH) {              // issue next chunk's loads; they stay
            const int coff = (ch + 1) * CK * HWSZ;   // in flight under compute
            p1a = *(const float4*)(g1a + coff);
            if (has1b) p1b = *(const float4*)(g1b + coff);
#pragma unroll
            for (int j = 0; j < 4; ++j)
                p2[j] = ok2[j] ? *(const float4*)(g2[j] + coff) : z4;
        }

        // ---- branch-free FMA phase ----
#pragma unroll
        for (int k = 0; k < CK; ++k) {
            float a[8], v[16];
            *(float4*)&a[0] = *(const float4*)&s1[k][yi][8 * xt];
            *(float4*)&a[4] = *(const float4*)&s1[k][yi][8 * xt + 4];
#pragma unroll
            for (int q = 0; q < 4; ++q)
                *(float4*)&v[4 * q] = *(const float4*)&s2[k][yi + dy][8 * xt + 4 * q];
#pragma unroll
            for (int dxi = 0; dxi < 9; ++dxi)
#pragma unroll
                for (int xi = 0; xi < 8; ++xi)
                    acc[dxi][xi] = fmaf(a[xi], v[xi + dxi], acc[dxi][xi]);
        }
    }

    // ---- epilogue: scale by 1/C, vectorized store ----
    const float scale = 1.0f / (float)CC;
#pragma unroll
    for (int dxi = 0; dxi < 9; ++dxi) {
        float4 o0 = make_float4(acc[dxi][0] * scale, acc[dxi][1] * scale,
                                acc[dxi][2] * scale, acc[dxi][3] * scale);
        float4 o1 = make_float4(acc[dxi][4] * scale, acc[dxi][5] * scale,
                                acc[dxi][6] * scale, acc[dxi][7] * scale);
        float* dst = out +
            (((b * 81 + dy * 9 + dxi) * HH + y0 + yi) * WW + x0 + 8 * xt);
        *(float4*)dst       = o0;
        *(float4*)(dst + 4) = o1;
    }
}

extern "C" void kernel_launch(void* const* d_in, const int* in_sizes, int n_in,
                              void* d_out, int out_size, void* d_ws, size_t ws_size,
                              hipStream_t stream) {
    const float* in1 = (const float*)d_in[0];
    const float* in2 = (const float*)d_in[1];
    float* out = (float*)d_out;
    dim3 grid(WW / TX, HH / TY, BB);  // 5 x 20 x 8 = 800 blocks
    corr_kernel<<<grid, NT, 0, stream>>>(in1, in2, out);
}

// Round 3
// 471.610 us; speedup vs baseline: 1.1204x; 1.1204x over previous
//
#include <hip/hip_runtime.h>
#include <stdint.h>

// FlowNet correlation, kernel_size=1, max_disp=4.
// out[b, (dy+4)*9+(dx+4), y, x] = (1/C) * sum_c in1[b,c,y,x]*in2[b,c,y+dy,x+dx]
//
// Block = 8x64 output tile, 576 thr = 9 waves, wave w owns dy=w (uniform).
// Thread = (dy, yi, xt): 8 consecutive x, acc[9 dx][8 x] in regs.
// C in CK=8 chunks, double-buffered LDS, staged with global_load_lds
// (zero VGPR cost -- R2's reg-prefetch spilled to scratch, +1GB HBM traffic).
// T3 2-phase: STAGE(next->buf^1); COMPUTE(buf); vmcnt(0); s_barrier.
// Padded LDS strides 68/76 floats kept conflict-free by mapping each linear
// LDS slot to its padded-layout global address per lane (source is per-lane,
// dest is linear: G21). Pad + OOB slots are exec-masked; s2 OOB slots are
// pre-zeroed once and never overwritten.

#define BB 8
#define CC 96
#define HH 160
#define WW 320
#define TY 8
#define TX 64
#define CK 8
#define NCH (CC / CK)        // 12
#define S1W 68               // 68*4B = 272B = 17 float4 slots per row
#define S2W 76               // 76*4B = 304B = 19 float4 slots per row
#define NT 576
#define HWSZ (HH * WW)

#define S1_F4 (CK * TY * S1W / 4)        // 1088 float4 slots
#define S2_F4 (CK * (TY + 8) * S2W / 4)  // 2432
#define N1 (S1_F4 / 64)                  // 17 wave-instructions (1KB each)
#define N2 (S2_F4 / 64)                  // 38
#define NINST (N1 + N2)                  // 55
#define NSTG 7                           // ceil(55/9) per wave

typedef const __attribute__((address_space(1))) void* gptr_t;
typedef __attribute__((address_space(3))) void* lptr_t;

__global__ __launch_bounds__(NT, 1)
void corr_kernel(const float* __restrict__ in1,
                 const float* __restrict__ in2,
                 float* __restrict__ out) {
    const int x0 = blockIdx.x * TX;
    const int y0 = blockIdx.y * TY;
    const int b  = blockIdx.z;

    const int tid  = threadIdx.x;
    const int wid  = tid >> 6;       // 0..8 = dy, uniform per wave
    const int lane = tid & 63;
    const int dy   = wid;
    const int yi   = lane >> 3;      // 0..7 output row in tile
    const int xt   = lane & 7;       // 0..7 -> 8-pixel x sub-block

    __shared__ __align__(16) float s1v[2][CK][TY][S1W];
    __shared__ __align__(16) float s2v[2][CK][TY + 8][S2W];

    // ---- per-thread staging descriptors (computed once) ----
    // wave-instruction j = wid + 9*t stages 1KB: linear LDS f4-slot
    // j*64 + lane  ->  padded-layout (k, row, xoff); pad/OOB lanes masked.
    int goff[NSTG];                  // c-chunk-relative element offset
    unsigned vmask = 0;
#pragma unroll
    for (int t = 0; t < NSTG; ++t) {
        goff[t] = 0;
        const int j = wid + 9 * t;
        if (j < N1) {                                    // in1 tile
            const int f4 = j * 64 + lane;                // 0..1087
            const int kr = f4 / 17, c4 = f4 % 17;
            const int k = kr >> 3, r = kr & 7;
            if (c4 < 16) {                               // not row pad
                vmask |= 1u << t;
                goff[t] = (k * HH + y0 + r) * WW + x0 + 4 * c4;
            }
        } else if (j < NINST) {                          // in2 halo tile
            const int f4 = (j - N1) * 64 + lane;         // 0..2431
            const int kr = f4 / 19, c4 = f4 % 19;
            const int k = kr >> 4, r = kr & 15;
            const int yy = y0 + r - 4;
            const int xs = x0 - 4 + 4 * c4;
            if (c4 < 18 && (unsigned)yy < (unsigned)HH &&
                (unsigned)xs <= (unsigned)(WW - 4)) {
                vmask |= 1u << t;
                goff[t] = (k * HH + yy) * WW + xs;
            }
        }
    }

    // ---- async stage of one C-chunk into buffer bs ----
    auto stage = [&](int c0, int bs) {
#pragma unroll
        for (int t = 0; t < NSTG; ++t) {
            const int j = wid + 9 * t;
            if (j >= NINST) continue;                    // uniform per wave
            const int cbase = (b * CC + c0) * HWSZ;
            const float* g;
            char* lb;                                    // wave-uniform base
            if (j < N1) {
                g  = in1 + cbase + goff[t];
                lb = (char*)(&s1v[bs][0][0][0]) + (size_t)j * 1024;
            } else {
                g  = in2 + cbase + goff[t];
                lb = (char*)(&s2v[bs][0][0][0]) + (size_t)(j - N1) * 1024;
            }
            if (vmask & (1u << t))                       // exec-masked lanes skip
                __builtin_amdgcn_global_load_lds((gptr_t)g, (lptr_t)lb, 16, 0, 0);
        }
    };

    // ---- pre-zero s2 buffers: OOB slots stay zero forever ----
    {
        const float4 z4 = make_float4(0.f, 0.f, 0.f, 0.f);
        float4* z = (float4*)&s2v[0][0][0][0];
        for (int i = tid; i < 2 * S2_F4; i += NT) z[i] = z4;
    }
    __syncthreads();            // zeros visible before DMA may land
    stage(0, 0);
    __syncthreads();            // compiler drains vmcnt(0): chunk 0 ready

    float acc[9][8];
#pragma unroll
    for (int i = 0; i < 9; ++i)
#pragma unroll
        for (int j = 0; j < 8; ++j) acc[i][j] = 0.0f;

    int bs = 0;
    for (int ch = 0; ch < NCH; ++ch) {
        if (ch + 1 < NCH) stage((ch + 1) * CK, bs ^ 1);  // in flight under FMAs

        const float (*cs1)[TY][S1W]     = s1v[bs];
        const float (*cs2)[TY + 8][S2W] = s2v[bs];
#pragma unroll
        for (int k = 0; k < CK; ++k) {
            float a[8], v[16];
            *(float4*)&a[0] = *(const float4*)&cs1[k][yi][8 * xt];
            *(float4*)&a[4] = *(const float4*)&cs1[k][yi][8 * xt + 4];
#pragma unroll
            for (int q = 0; q < 4; ++q)
                *(float4*)&v[4 * q] =
                    *(const float4*)&cs2[k][yi + dy][8 * xt + 4 * q];
#pragma unroll
            for (int dxi = 0; dxi < 9; ++dxi)
#pragma unroll
                for (int xi = 0; xi < 8; ++xi)
                    acc[dxi][xi] = fmaf(a[xi], v[xi + dxi], acc[dxi][xi]);
        }

        if (ch + 1 < NCH) {
            asm volatile("s_waitcnt vmcnt(0)" ::: "memory"); // next chunk landed
            __builtin_amdgcn_s_barrier();                    // all waves done w/ bs
            asm volatile("" ::: "memory");                   // no hoist past barrier
        }
        bs ^= 1;
    }

    // ---- epilogue: scale by 1/C, vectorized store ----
    const float scale = 1.0f / (float)CC;
#pragma unroll
    for (int dxi = 0; dxi < 9; ++dxi) {
        float4 o0 = make_float4(acc[dxi][0] * scale, acc[dxi][1] * scale,
                                acc[dxi][2] * scale, acc[dxi][3] * scale);
        float4 o1 = make_float4(acc[dxi][4] * scale, acc[dxi][5] * scale,
                                acc[dxi][6] * scale, acc[dxi][7] * scale);
        float* dst = out +
            (((b * 81 + dy * 9 + dxi) * HH + y0 + yi) * WW + x0 + 8 * xt);
        *(float4*)dst       = o0;
        *(float4*)(dst + 4) = o1;
    }
}

extern "C" void kernel_launch(void* const* d_in, const int* in_sizes, int n_in,
                              void* d_out, int out_size, void* d_ws, size_t ws_size,
                              hipStream_t stream) {
    const float* in1 = (const float*)d_in[0];
    const float* in2 = (const float*)d_in[1];
    float* out = (float*)d_out;
    dim3 grid(WW / TX, HH / TY, BB);  // 5 x 20 x 8 = 800 blocks
    corr_kernel<<<grid, NT, 0, stream>>>(in1, in2, out);
}